// Round 6
// baseline (2916.432 us; speedup 1.0000x reference)
//
#include <hip/hip_runtime.h>
#include <hip/hip_bf16.h>
#include <stdint.h>
#include <stddef.h>

// tidigitsRNNPT: Elman RNN (B=128, SEQ=254, FEAT=39, HID=1024) -> FC1 -> FC2 -> log_softmax
//
// R5: irreducible-round-trip scan. R4 post-mortem: sc0sc1 stores write THROUGH
// to HBM (WRITE_SIZE=195MB proves it) -> store-visible ~1us; polls served by IF
// (FETCH small). R4's remaining overhead was self-inflicted drains: poison ack
// gated poll round 1, __syncthreads re-drained it, LDS share coupled waves to
// the slowest. This round the step is stripped to the one mandatory exchange:
//  - NO barriers, NO LDS: each wave loads all 32 h-frags itself and self-clocks.
//  - poison -> slot s+3 (NRING=6): ack hidden under data wait; ordering safe
//    (two poll-drains separate poison from any s+3-data store).
//  - xp load after detect (acc init 0, xp added at tanh) -> off the drain path.
//  - immediate-offset loads keep one base addr; a[32]+breg[32] ~300 VGPR @ 1 wave/SIMD.

typedef unsigned short u16;
typedef unsigned int u32;
typedef __attribute__((ext_vector_type(2))) unsigned int u32x2;
typedef __attribute__((ext_vector_type(4))) float f32x4;
typedef __attribute__((ext_vector_type(4))) unsigned short u16x4;
typedef __attribute__((ext_vector_type(8))) short short8;

#define SEQ   254
#define BATCH 128
#define HID   1024
#define FEAT  39
#define FC1N  100
#define FC1P  112
#define NCLS  10
#define NRING 6
#define SENT  0xAAAAAAAAu

// ---- workspace layout ----
#define OFF_RING  ((size_t)0)                                      // 6*128*1024 bf16 = 1.5MB
#define OFF_OUTS  (OFF_RING + (size_t)NRING * BATCH * HID * 2)     // 66.6MB
#define OFF_WHH   (OFF_OUTS + (size_t)SEQ * BATCH * HID * 2)       // 2MB
#define OFF_XP    (OFF_WHH + (size_t)HID * HID * 2)                // 66.6MB
#define OFF_PART  (OFF_XP + (size_t)SEQ * BATCH * HID * 2)         // 14.6MB

__device__ inline u16 f2bf(float f){
  union { float f; unsigned u; } v; v.f = f;
  unsigned u = v.u;
  u += 0x7fffu + ((u >> 16) & 1u);
  return (u16)(u >> 16);
}
__device__ inline float bf2f(u16 h){
  union { unsigned u; float f; } v; v.u = ((unsigned)h) << 16;
  return v.f;
}
__device__ inline float fast_tanh(float x){
  // exact 0 for tiny |x|; smallest nonzero |out| ~5.9e-8 => bf16 0xAAAA
  // (-3.0e-13) unproducible => safe sentinel. h0 in [0,1) also safe.
  float e = __expf(2.0f * x);
  return 1.0f - 2.0f / (e + 1.0f);
}

// ---- IF-coherent (system-scope) ops ----
__device__ inline short8 ld_cohx4_off(const u16* p, int imm_bytes){
  short8 r;
  asm volatile("global_load_dwordx4 %0, %1, off offset:%2 sc0 sc1"
               : "=v"(r) : "v"(p), "i"(imm_bytes) : "memory");
  return r;
}
__device__ inline void st_cohx2(u16* p, u32x2 v){
  asm volatile("global_store_dwordx2 %0, %1, off sc0 sc1" :: "v"(p), "v"(v) : "memory");
}

__device__ inline u32 frag_bad(short8 v){
  union { short8 s; u32 w[4]; } u; u.s = v;
  return (u32)((u.w[0] == SENT) | (u.w[1] == SENT) | (u.w[2] == SENT) | (u.w[3] == SENT));
}

// ---------------- fp32 -> bf16 bulk convert ----------------
__global__ void cvt_f32_bf16_kernel(const float* __restrict__ in, u16* __restrict__ out, int n4){
  int i = blockIdx.x * blockDim.x + threadIdx.x;
  if (i < n4){
    f32x4 v = *(const f32x4*)(in + (size_t)i * 4);
    u16x4 o;
    o[0] = f2bf(v[0]); o[1] = f2bf(v[1]); o[2] = f2bf(v[2]); o[3] = f2bf(v[3]);
    *(u16x4*)(out + (size_t)i * 4) = o;
  }
}

// ---------------- xproj: [SEQ][BATCH][HID] bf16 (includes both biases) ----------------
__global__ __launch_bounds__(1024) void xproj_kernel(const float* __restrict__ x,
                                                     const float* __restrict__ W_ih,
                                                     const float* __restrict__ b_ih,
                                                     const float* __restrict__ b_hh,
                                                     u16* __restrict__ xp){
  const int s = blockIdx.x;
  __shared__ float xs[BATCH * (FEAT + 1)];
  for (int i = threadIdx.x; i < BATCH * FEAT; i += 1024){
    int b = i / FEAT, f = i - b * FEAT;
    xs[b * (FEAT + 1) + f] = x[((size_t)b * SEQ + s) * FEAT + f];
  }
  __syncthreads();
  const int h = threadIdx.x;
  float w[FEAT];
  #pragma unroll
  for (int f = 0; f < FEAT; ++f) w[f] = W_ih[h * FEAT + f];
  const float bias = b_ih[h] + b_hh[h];
  for (int b = 0; b < BATCH; ++b){
    float acc = bias;
    #pragma unroll
    for (int f = 0; f < FEAT; ++f) acc += xs[b * (FEAT + 1) + f] * w[f];
    xp[((size_t)s * BATCH + b) * HID + h] = f2bf(acc);
  }
}

// ---------------- barrier-free self-clocking RNN scan ----------------
// 128 blocks x 4 waves; every wave fully independent. Block (bgrp=bid&7,
// hgrp=bid>>3); wave owns h rows [hgrp*64+wid*16, +16) x batches [bgrp*16,+16).
// Per step: poison slot s+3 (own 8B), poll ALL 32 frags of slot s until no
// sentinel dword, MFMA from VGPRs, tanh(+xp), 8B store to slot s+1 + outs.
__global__ __launch_bounds__(256, 1) void scan_kernel(const u16* __restrict__ whh,
                                                      const u16* __restrict__ xp,
                                                      u16* __restrict__ ring,
                                                      u16* __restrict__ outs){
  const int bid  = blockIdx.x;
  const int bgrp = bid & 7;
  const int hgrp = bid >> 3;
  const int wid  = threadIdx.x >> 6;
  const int lane = threadIdx.x & 63;
  const int lr = lane & 15;
  const int lg = lane >> 4;
  const int b_base = bgrp * 16;
  const int h_base = hgrp * 64 + wid * 16;

  // W_hh fragments, register-resident
  short8 breg[32];
  {
    const u16* wp = whh + (size_t)(h_base + lr) * HID + lg * 8;
    #pragma unroll
    for (int kk = 0; kk < 32; ++kk) breg[kk] = *(const short8*)(wp + kk * 32);
  }

  const int b_o = b_base + lr;               // D col
  const int h_o = h_base + lg * 4;           // D rows (4 consec h)
  const size_t poll_off = (size_t)(b_base + lr) * HID + lg * 8;
  const size_t st_off   = (size_t)b_o * HID + h_o;

  const u32x2 sent2 = {SENT, SENT};

  for (int s = 0; s < SEQ; ++s){
    // 1) poison own 8B in slot s+3 (ack hides under the data wait; ordering
    //    vs s+3-data stores guaranteed by two intervening poll drains)
    st_cohx2(ring + (size_t)((s + 3) % NRING) * (BATCH * HID) + st_off, sent2);

    // 2) poll slot s: all 32 fragments, retry-all until clean
    const u16* pa = ring + (size_t)(s % NRING) * (BATCH * HID) + poll_off;
    short8 a[32];
    for (;;){
      #pragma unroll
      for (int kk = 0; kk < 32; ++kk) a[kk] = ld_cohx4_off(pa, kk * 64);
      asm volatile("s_waitcnt vmcnt(0)" ::: "memory");
      __builtin_amdgcn_sched_barrier(0);
      u32 any = 0;
      #pragma unroll
      for (int kk = 0; kk < 32; ++kk) any |= frag_bad(a[kk]);
      if (__ballot(any) == 0ull) break;
    }
    __builtin_amdgcn_sched_barrier(0);

    // 3) xp load (off drain path; hidden under MFMA chain)
    u16x4 xv = *(const u16x4*)(xp + ((size_t)s * BATCH + b_o) * HID + h_o);

    // 4) MFMA over 32 fragments, two interleaved chains
    f32x4 acc0 = {0.f, 0.f, 0.f, 0.f}, acc1 = {0.f, 0.f, 0.f, 0.f};
    #pragma unroll
    for (int kk = 0; kk < 32; kk += 2){
      acc0 = __builtin_amdgcn_mfma_f32_16x16x32_bf16(breg[kk],     a[kk],     acc0, 0, 0, 0);
      acc1 = __builtin_amdgcn_mfma_f32_16x16x32_bf16(breg[kk + 1], a[kk + 1], acc1, 0, 0, 0);
    }

    // 5) tanh(+xp) -> pack -> ring store (coherent) + outs store (plain)
    u32x2 d;
    {
      float v0 = fast_tanh(acc0[0] + acc1[0] + bf2f(xv[0]));
      float v1 = fast_tanh(acc0[1] + acc1[1] + bf2f(xv[1]));
      float v2 = fast_tanh(acc0[2] + acc1[2] + bf2f(xv[2]));
      float v3 = fast_tanh(acc0[3] + acc1[3] + bf2f(xv[3]));
      d[0] = (u32)f2bf(v0) | ((u32)f2bf(v1) << 16);
      d[1] = (u32)f2bf(v2) | ((u32)f2bf(v3) << 16);
    }
    st_cohx2(ring + (size_t)((s + 1) % NRING) * (BATCH * HID) + st_off, d);
    *(u32x2*)(outs + ((size_t)s * BATCH + b_o) * HID + h_o) = d;
  }
}

// ---------------- FC1 partials via MFMA ----------------
__global__ __launch_bounds__(256) void fc1_kernel(const u16* __restrict__ outs,
                                                  const float* __restrict__ W1,
                                                  float* __restrict__ part){
  const int s = blockIdx.x;
  const int wid  = threadIdx.x >> 6;
  const int lane = threadIdx.x & 63;
  const int lr = lane & 15;
  const int lg = lane >> 4;

  f32x4 acc[2][7];
  const f32x4 zero = {0.f, 0.f, 0.f, 0.f};
  #pragma unroll
  for (int i = 0; i < 2; ++i)
    #pragma unroll
    for (int n = 0; n < 7; ++n) acc[i][n] = zero;

  const u16* pa0 = outs + ((size_t)s * BATCH + wid * 32 + lr) * HID + lg * 8;
  const u16* pa1 = pa0 + 16 * HID;

  for (int kk = 0; kk < 32; ++kk){
    short8 a0 = *(const short8*)(pa0 + kk * 32);
    short8 a1 = *(const short8*)(pa1 + kk * 32);
    #pragma unroll
    for (int nt = 0; nt < 7; ++nt){
      const int j = nt * 16 + lr;
      short8 bf;
      if (j < FC1N){
        const float* wp = W1 + (size_t)j * (SEQ * HID) + (size_t)s * HID + kk * 32 + lg * 8;
        f32x4 w0 = *(const f32x4*)wp;
        f32x4 w1 = *(const f32x4*)(wp + 4);
        #pragma unroll
        for (int r = 0; r < 4; ++r){ bf[r] = (short)f2bf(w0[r]); bf[r + 4] = (short)f2bf(w1[r]); }
      } else {
        #pragma unroll
        for (int r = 0; r < 8; ++r) bf[r] = 0;
      }
      acc[0][nt] = __builtin_amdgcn_mfma_f32_16x16x32_bf16(a0, bf, acc[0][nt], 0, 0, 0);
      acc[1][nt] = __builtin_amdgcn_mfma_f32_16x16x32_bf16(a1, bf, acc[1][nt], 0, 0, 0);
    }
  }

  #pragma unroll
  for (int i = 0; i < 2; ++i)
    #pragma unroll
    for (int nt = 0; nt < 7; ++nt)
      #pragma unroll
      for (int r = 0; r < 4; ++r){
        const int b = wid * 32 + i * 16 + lg * 4 + r;
        const int j = nt * 16 + lr;
        part[((size_t)s * BATCH + b) * FC1P + j] = acc[i][nt][r];
      }
}

// ---------------- reduce partials + bias + relu + FC2 + log_softmax ----------------
__global__ __launch_bounds__(128) void reduce_kernel(const float* __restrict__ part,
                                                     const float* __restrict__ b1,
                                                     const float* __restrict__ W2,
                                                     const float* __restrict__ b2,
                                                     float* __restrict__ out){
  const int b = blockIdx.x;
  const int j = threadIdx.x;
  __shared__ float h1[FC1N];
  __shared__ float lgt[NCLS];

  if (j < FC1P){
    const float* p = part + (size_t)b * FC1P + j;
    float acc = 0.f;
    #pragma unroll 4
    for (int s = 0; s < SEQ; ++s) acc += p[(size_t)s * BATCH * FC1P];
    if (j < FC1N) h1[j] = fmaxf(acc + b1[j], 0.f);
  }
  __syncthreads();
  if (j < NCLS){
    float v = b2[j];
    for (int q = 0; q < FC1N; ++q) v += h1[q] * W2[j * FC1N + q];
    lgt[j] = v;
  }
  __syncthreads();
  if (j < NCLS){
    float m = lgt[0];
    #pragma unroll
    for (int q = 1; q < NCLS; ++q) m = fmaxf(m, lgt[q]);
    float sum = 0.f;
    #pragma unroll
    for (int q = 0; q < NCLS; ++q) sum += __expf(lgt[q] - m);
    out[b * NCLS + j] = lgt[j] - (m + __logf(sum));
  }
}

extern "C" void kernel_launch(void* const* d_in, const int* in_sizes, int n_in,
                              void* d_out, int out_size, void* d_ws, size_t ws_size,
                              hipStream_t stream){
  (void)in_sizes; (void)n_in; (void)out_size; (void)ws_size;
  const float* x   = (const float*)d_in[0];
  const float* h0  = (const float*)d_in[1];
  const float* Wih = (const float*)d_in[2];
  const float* Whh = (const float*)d_in[3];
  const float* bih = (const float*)d_in[4];
  const float* bhh = (const float*)d_in[5];
  const float* W1  = (const float*)d_in[6];
  const float* b1  = (const float*)d_in[7];
  const float* W2  = (const float*)d_in[8];
  const float* b2  = (const float*)d_in[9];
  float* out = (float*)d_out;

  char* ws = (char*)d_ws;
  u16*  ring = (u16*)(ws + OFF_RING);
  u16*  outs = (u16*)(ws + OFF_OUTS);
  u16*  whh  = (u16*)(ws + OFF_WHH);
  u16*  xp   = (u16*)(ws + OFF_XP);
  float* part = (float*)(ws + OFF_PART);

  // poison ring slots 1..5 (slot 0 = h0)
  hipMemsetAsync(ring + (size_t)BATCH * HID, 0xAA, (size_t)(NRING - 1) * BATCH * HID * 2, stream);
  cvt_f32_bf16_kernel<<<1024, 256, 0, stream>>>(Whh, whh, (HID * HID) / 4);
  cvt_f32_bf16_kernel<<<128, 256, 0, stream>>>(h0, ring, (BATCH * HID) / 4);
  xproj_kernel<<<SEQ, 1024, 0, stream>>>(x, Wih, bih, bhh, xp);
  scan_kernel<<<128, 256, 0, stream>>>(whh, xp, ring, outs);
  fc1_kernel<<<SEQ, 256, 0, stream>>>(outs, W1, part);
  reduce_kernel<<<BATCH, 128, 0, stream>>>(part, b1, W2, b2, out);
}

// Round 7
// 1538.314 us; speedup vs baseline: 1.8959x; 1.8959x over previous
//
#include <hip/hip_runtime.h>
#include <hip/hip_bf16.h>
#include <stdint.h>
#include <stddef.h>

// tidigitsRNNPT: Elman RNN (B=128, SEQ=254, FEAT=39, HID=1024) -> FC1 -> FC2 -> log_softmax
//
// R6: R4 structure (best measured: distributed poll + LDS share + 1 barrier) with
// the ring exchange retired at the INFINITY-FABRIC point instead of HBM.
// R5 post-mortem: per-wave-loads-all regressed (4x ring reads, VGPR 140 w/ spills).
// R4 post-mortem: WRITE_SIZE=195MB proved sc0sc1 stores write through to HBM ->
// store-visible ~1us on the critical path, poison ack gating poll round 1.
// Fix: ring data + poison stores become no-return global_atomic_swap_x2 --
// atomics complete at the IF (line stays dirty there, no HBM write-through);
// sc0sc1 poll loads read at the IF and see them immediately.
// Test: WRITE_SIZE should collapse 195 -> ~70-80MB (outs only).

typedef unsigned short u16;
typedef unsigned int u32;
typedef __attribute__((ext_vector_type(2))) unsigned int u32x2;
typedef __attribute__((ext_vector_type(4))) float f32x4;
typedef __attribute__((ext_vector_type(4))) unsigned short u16x4;
typedef __attribute__((ext_vector_type(8))) short short8;

#define SEQ   254
#define BATCH 128
#define HID   1024
#define FEAT  39
#define FC1N  100
#define FC1P  112
#define NCLS  10
#define NRING 6
#define SENT  0xAAAAAAAAu

// ---- workspace layout ----
#define OFF_RING  ((size_t)0)                                      // 6*128*1024 bf16 = 1.5MB
#define OFF_OUTS  (OFF_RING + (size_t)NRING * BATCH * HID * 2)     // 66.6MB
#define OFF_WHH   (OFF_OUTS + (size_t)SEQ * BATCH * HID * 2)       // 2MB
#define OFF_XP    (OFF_WHH + (size_t)HID * HID * 2)                // 66.6MB
#define OFF_PART  (OFF_XP + (size_t)SEQ * BATCH * HID * 2)         // 14.6MB

__device__ inline u16 f2bf(float f){
  union { float f; unsigned u; } v; v.f = f;
  unsigned u = v.u;
  u += 0x7fffu + ((u >> 16) & 1u);
  return (u16)(u >> 16);
}
__device__ inline float bf2f(u16 h){
  union { unsigned u; float f; } v; v.u = ((unsigned)h) << 16;
  return v.f;
}
__device__ inline float fast_tanh(float x){
  // exact 0 for tiny |x|; smallest nonzero |out| ~5.9e-8 => bf16 0xAAAA
  // (-3.0e-13) unproducible => safe sentinel. h0 in [0,1) also safe.
  float e = __expf(2.0f * x);
  return 1.0f - 2.0f / (e + 1.0f);
}

// ---- exchange primitives ----
// loads: sc0sc1 (bypass L1/L2, read at IF). stores: no-return atomic swap --
// executes at the IF coherence point, NO HBM write-through on critical path.
__device__ inline short8 ld_cohx4(const u16* p){
  short8 r;
  asm volatile("global_load_dwordx4 %0, %1, off sc0 sc1" : "=v"(r) : "v"(p) : "memory");
  return r;
}
__device__ inline void at_swapx2(u16* p, u32x2 v){
  asm volatile("global_atomic_swap_x2 %0, %1, off" :: "v"(p), "v"(v) : "memory");
}

__device__ inline u32 frag_bad(short8 v){
  union { short8 s; u32 w[4]; } u; u.s = v;
  return (u32)((u.w[0] == SENT) | (u.w[1] == SENT) | (u.w[2] == SENT) | (u.w[3] == SENT));
}

// ---------------- fp32 -> bf16 bulk convert ----------------
__global__ void cvt_f32_bf16_kernel(const float* __restrict__ in, u16* __restrict__ out, int n4){
  int i = blockIdx.x * blockDim.x + threadIdx.x;
  if (i < n4){
    f32x4 v = *(const f32x4*)(in + (size_t)i * 4);
    u16x4 o;
    o[0] = f2bf(v[0]); o[1] = f2bf(v[1]); o[2] = f2bf(v[2]); o[3] = f2bf(v[3]);
    *(u16x4*)(out + (size_t)i * 4) = o;
  }
}

// ---------------- xproj: [SEQ][BATCH][HID] bf16 (includes both biases) ----------------
__global__ __launch_bounds__(1024) void xproj_kernel(const float* __restrict__ x,
                                                     const float* __restrict__ W_ih,
                                                     const float* __restrict__ b_ih,
                                                     const float* __restrict__ b_hh,
                                                     u16* __restrict__ xp){
  const int s = blockIdx.x;
  __shared__ float xs[BATCH * (FEAT + 1)];
  for (int i = threadIdx.x; i < BATCH * FEAT; i += 1024){
    int b = i / FEAT, f = i - b * FEAT;
    xs[b * (FEAT + 1) + f] = x[((size_t)b * SEQ + s) * FEAT + f];
  }
  __syncthreads();
  const int h = threadIdx.x;
  float w[FEAT];
  #pragma unroll
  for (int f = 0; f < FEAT; ++f) w[f] = W_ih[h * FEAT + f];
  const float bias = b_ih[h] + b_hh[h];
  for (int b = 0; b < BATCH; ++b){
    float acc = bias;
    #pragma unroll
    for (int f = 0; f < FEAT; ++f) acc += xs[b * (FEAT + 1) + f] * w[f];
    xp[((size_t)s * BATCH + b) * HID + h] = f2bf(acc);
  }
}

// ---------------- sentinel-ring persistent RNN scan ----------------
// 128 blocks. Block (bgrp=bid&7, hgrp=bid>>3) owns h[16 b][64 h]. Per step:
// poison slot s+2 (own 8B, atomic; drained by poll round 1's vmcnt(0) BEFORE
// the s+1 data store issues -> can never clobber peer data), distributed poll
// of slot s (wave polls its 8 frags), LDS share (lane-linear, conflict-free),
// one syncthreads, MFMA from LDS, tanh(+xp), atomic ring store + plain outs.
__global__ __launch_bounds__(256, 1) void scan_kernel(const u16* __restrict__ whh,
                                                      const u16* __restrict__ xp,
                                                      u16* __restrict__ ring,
                                                      u16* __restrict__ outs){
  __shared__ u16 hsh[2][32][512];     // [buf][frag kk][lane*8] : 64KB

  const int bid  = blockIdx.x;
  const int bgrp = bid & 7;
  const int hgrp = bid >> 3;
  const int wid  = threadIdx.x >> 6;
  const int lane = threadIdx.x & 63;
  const int lr = lane & 15;
  const int lg = lane >> 4;
  const int b_base = bgrp * 16;
  const int h_base = hgrp * 64 + wid * 16;
  const int kk0 = wid * 8;            // this wave's poll quarter

  // W_hh A-fragments, register-resident
  short8 breg[32];
  {
    const u16* wp = whh + (size_t)(h_base + lr) * HID + lg * 8;
    #pragma unroll
    for (int kk = 0; kk < 32; ++kk) breg[kk] = *(const short8*)(wp + kk * 32);
  }

  const int b_o = b_base + lr;                    // D col
  const int h_o = hgrp * 64 + wid * 16 + lg * 4;  // D rows (4 consec h)
  const size_t poll_off = (size_t)(b_base + lr) * HID + lg * 8;
  const size_t st_off   = (size_t)b_o * HID + h_o;

  const u32x2 sent2 = {SENT, SENT};

  // prologue: xv for s=0
  u16x4 xv = *(const u16x4*)(xp + (size_t)b_o * HID + h_o);

  for (int s = 0; s < SEQ; ++s){
    // 1) poison own 8B in slot s+2 (atomic -> IF; ack overlaps poll round 1)
    at_swapx2(ring + (size_t)((s + 2) % NRING) * (BATCH * HID) + st_off, sent2);

    // 2) distributed poll of slot s (this wave's 8 fragments)
    const u16* pp = ring + (size_t)(s % NRING) * (BATCH * HID) + poll_off;
    short8 f[8];
    u32 bad = 0xFFu;
    while (bad){
      #pragma unroll
      for (int i = 0; i < 8; ++i)
        if (bad & (1u << i)) f[i] = ld_cohx4(pp + (kk0 + i) * 32);
      asm volatile("s_waitcnt vmcnt(0)" ::: "memory");
      __builtin_amdgcn_sched_barrier(0);
      u32 nb = 0;
      #pragma unroll
      for (int i = 0; i < 8; ++i)
        if (bad & (1u << i)) nb |= (__ballot(frag_bad(f[i])) != 0ull) ? (1u << i) : 0u;
      bad = nb;
    }

    // 3) share via LDS (lane-linear: conflict-free), double-buffered
    u16* wb = &hsh[s & 1][0][0];
    #pragma unroll
    for (int i = 0; i < 8; ++i)
      *(short8*)(wb + (size_t)(kk0 + i) * 512 + lane * 8) = f[i];

    // prefetch xp for next step
    u16x4 xv_next;
    if (s + 1 < SEQ)
      xv_next = *(const u16x4*)(xp + ((size_t)(s + 1) * BATCH + b_o) * HID + h_o);

    __syncthreads();

    // 4) MFMA over all 32 fragments from LDS
    f32x4 acc0, acc1 = {0.f, 0.f, 0.f, 0.f};
    acc0[0] = bf2f(xv[0]); acc0[1] = bf2f(xv[1]); acc0[2] = bf2f(xv[2]); acc0[3] = bf2f(xv[3]);
    #pragma unroll
    for (int kk = 0; kk < 32; kk += 2){
      short8 a0 = *(const short8*)(wb + (size_t)kk * 512 + lane * 8);
      short8 a1 = *(const short8*)(wb + (size_t)(kk + 1) * 512 + lane * 8);
      acc0 = __builtin_amdgcn_mfma_f32_16x16x32_bf16(breg[kk],     a0, acc0, 0, 0, 0);
      acc1 = __builtin_amdgcn_mfma_f32_16x16x32_bf16(breg[kk + 1], a1, acc1, 0, 0, 0);
    }

    // 5) tanh -> pack -> atomic ring store (IF-resident) + plain outs store
    u32x2 d;
    {
      float v0 = fast_tanh(acc0[0] + acc1[0]);
      float v1 = fast_tanh(acc0[1] + acc1[1]);
      float v2 = fast_tanh(acc0[2] + acc1[2]);
      float v3 = fast_tanh(acc0[3] + acc1[3]);
      d[0] = (u32)f2bf(v0) | ((u32)f2bf(v1) << 16);
      d[1] = (u32)f2bf(v2) | ((u32)f2bf(v3) << 16);
    }
    at_swapx2(ring + (size_t)((s + 1) % NRING) * (BATCH * HID) + st_off, d);
    *(u32x2*)(outs + ((size_t)s * BATCH + b_o) * HID + h_o) = d;

    xv = xv_next;
  }
}

// ---------------- FC1 partials via MFMA ----------------
__global__ __launch_bounds__(256) void fc1_kernel(const u16* __restrict__ outs,
                                                  const float* __restrict__ W1,
                                                  float* __restrict__ part){
  const int s = blockIdx.x;
  const int wid  = threadIdx.x >> 6;
  const int lane = threadIdx.x & 63;
  const int lr = lane & 15;
  const int lg = lane >> 4;

  f32x4 acc[2][7];
  const f32x4 zero = {0.f, 0.f, 0.f, 0.f};
  #pragma unroll
  for (int i = 0; i < 2; ++i)
    #pragma unroll
    for (int n = 0; n < 7; ++n) acc[i][n] = zero;

  const u16* pa0 = outs + ((size_t)s * BATCH + wid * 32 + lr) * HID + lg * 8;
  const u16* pa1 = pa0 + 16 * HID;

  for (int kk = 0; kk < 32; ++kk){
    short8 a0 = *(const short8*)(pa0 + kk * 32);
    short8 a1 = *(const short8*)(pa1 + kk * 32);
    #pragma unroll
    for (int nt = 0; nt < 7; ++nt){
      const int j = nt * 16 + lr;
      short8 bf;
      if (j < FC1N){
        const float* wp = W1 + (size_t)j * (SEQ * HID) + (size_t)s * HID + kk * 32 + lg * 8;
        f32x4 w0 = *(const f32x4*)wp;
        f32x4 w1 = *(const f32x4*)(wp + 4);
        #pragma unroll
        for (int r = 0; r < 4; ++r){ bf[r] = (short)f2bf(w0[r]); bf[r + 4] = (short)f2bf(w1[r]); }
      } else {
        #pragma unroll
        for (int r = 0; r < 8; ++r) bf[r] = 0;
      }
      acc[0][nt] = __builtin_amdgcn_mfma_f32_16x16x32_bf16(a0, bf, acc[0][nt], 0, 0, 0);
      acc[1][nt] = __builtin_amdgcn_mfma_f32_16x16x32_bf16(a1, bf, acc[1][nt], 0, 0, 0);
    }
  }

  #pragma unroll
  for (int i = 0; i < 2; ++i)
    #pragma unroll
    for (int nt = 0; nt < 7; ++nt)
      #pragma unroll
      for (int r = 0; r < 4; ++r){
        const int b = wid * 32 + i * 16 + lg * 4 + r;
        const int j = nt * 16 + lr;
        part[((size_t)s * BATCH + b) * FC1P + j] = acc[i][nt][r];
      }
}

// ---------------- reduce partials + bias + relu + FC2 + log_softmax ----------------
__global__ __launch_bounds__(128) void reduce_kernel(const float* __restrict__ part,
                                                     const float* __restrict__ b1,
                                                     const float* __restrict__ W2,
                                                     const float* __restrict__ b2,
                                                     float* __restrict__ out){
  const int b = blockIdx.x;
  const int j = threadIdx.x;
  __shared__ float h1[FC1N];
  __shared__ float lgt[NCLS];

  if (j < FC1P){
    const float* p = part + (size_t)b * FC1P + j;
    float acc = 0.f;
    #pragma unroll 4
    for (int s = 0; s < SEQ; ++s) acc += p[(size_t)s * BATCH * FC1P];
    if (j < FC1N) h1[j] = fmaxf(acc + b1[j], 0.f);
  }
  __syncthreads();
  if (j < NCLS){
    float v = b2[j];
    for (int q = 0; q < FC1N; ++q) v += h1[q] * W2[j * FC1N + q];
    lgt[j] = v;
  }
  __syncthreads();
  if (j < NCLS){
    float m = lgt[0];
    #pragma unroll
    for (int q = 1; q < NCLS; ++q) m = fmaxf(m, lgt[q]);
    float sum = 0.f;
    #pragma unroll
    for (int q = 0; q < NCLS; ++q) sum += __expf(lgt[q] - m);
    out[b * NCLS + j] = lgt[j] - (m + __logf(sum));
  }
}

extern "C" void kernel_launch(void* const* d_in, const int* in_sizes, int n_in,
                              void* d_out, int out_size, void* d_ws, size_t ws_size,
                              hipStream_t stream){
  (void)in_sizes; (void)n_in; (void)out_size; (void)ws_size;
  const float* x   = (const float*)d_in[0];
  const float* h0  = (const float*)d_in[1];
  const float* Wih = (const float*)d_in[2];
  const float* Whh = (const float*)d_in[3];
  const float* bih = (const float*)d_in[4];
  const float* bhh = (const float*)d_in[5];
  const float* W1  = (const float*)d_in[6];
  const float* b1  = (const float*)d_in[7];
  const float* W2  = (const float*)d_in[8];
  const float* b2  = (const float*)d_in[9];
  float* out = (float*)d_out;

  char* ws = (char*)d_ws;
  u16*  ring = (u16*)(ws + OFF_RING);
  u16*  outs = (u16*)(ws + OFF_OUTS);
  u16*  whh  = (u16*)(ws + OFF_WHH);
  u16*  xp   = (u16*)(ws + OFF_XP);
  float* part = (float*)(ws + OFF_PART);

  // poison ring slots 1..5 (slot 0 = h0)
  hipMemsetAsync(ring + (size_t)BATCH * HID, 0xAA, (size_t)(NRING - 1) * BATCH * HID * 2, stream);
  cvt_f32_bf16_kernel<<<1024, 256, 0, stream>>>(Whh, whh, (HID * HID) / 4);
  cvt_f32_bf16_kernel<<<128, 256, 0, stream>>>(h0, ring, (BATCH * HID) / 4);
  xproj_kernel<<<SEQ, 1024, 0, stream>>>(x, Wih, bih, bhh, xp);
  scan_kernel<<<128, 256, 0, stream>>>(whh, xp, ring, outs);
  fc1_kernel<<<SEQ, 256, 0, stream>>>(outs, W1, part);
  reduce_kernel<<<BATCH, 128, 0, stream>>>(part, b1, W2, b2, out);
}